// Round 1
// baseline (258.487 us; speedup 1.0000x reference)
//
#include <hip/hip_runtime.h>
#include <hip/hip_bf16.h>
#include <math.h>

// Problem constants
#define BB 64     // batch
#define NN 64     // nodes
#define HH 256    // hidden
#define FF 8      // features
// E = NN*(NN-1) = 4032

// ---------------------------------------------------------------------------
// Generic tiled fp32 GEMM: C[M,N] = act(scale*(A[M,K]@B[K,N]) + bias[N])
// ACT: 0 = none, 1 = relu. Tile 64x64, 256 threads, 4x4 microtile.
// ---------------------------------------------------------------------------
template<int ACT>
__global__ __launch_bounds__(256) void gemm_kernel(
    const float* __restrict__ A, const float* __restrict__ B,
    const float* __restrict__ bias, float* __restrict__ C,
    int M, int N, int K, float scale)
{
    __shared__ float As[16][68];
    __shared__ float Bs[16][68];
    const int bm = blockIdx.y * 64;
    const int bn = blockIdx.x * 64;
    const int tid = threadIdx.x;
    const int tx = tid & 15, ty = tid >> 4;

    const int lm  = tid >> 2;          // 0..63 (A row within tile)
    const int lk  = (tid & 3) * 4;     // 0,4,8,12 (A k offset)
    const int ln  = (tid & 15) * 4;    // B col within tile
    const int lkb = tid >> 4;          // 0..15 (B k row)

    float acc[4][4] = {};

    for (int k0 = 0; k0 < K; k0 += 16) {
        float4 a4 = *(const float4*)(A + (size_t)(bm + lm) * K + k0 + lk);
        As[lk + 0][lm] = a4.x;
        As[lk + 1][lm] = a4.y;
        As[lk + 2][lm] = a4.z;
        As[lk + 3][lm] = a4.w;
        float4 b4 = *(const float4*)(B + (size_t)(k0 + lkb) * N + bn + ln);
        *(float4*)&Bs[lkb][ln] = b4;
        __syncthreads();
#pragma unroll
        for (int k = 0; k < 16; ++k) {
            float a[4], b[4];
#pragma unroll
            for (int i = 0; i < 4; ++i) a[i] = As[k][ty * 4 + i];
#pragma unroll
            for (int j = 0; j < 4; ++j) b[j] = Bs[k][tx * 4 + j];
#pragma unroll
            for (int i = 0; i < 4; ++i)
#pragma unroll
                for (int j = 0; j < 4; ++j)
                    acc[i][j] += a[i] * b[j];
        }
        __syncthreads();
    }

#pragma unroll
    for (int i = 0; i < 4; ++i) {
        int row = bm + ty * 4 + i;
#pragma unroll
        for (int j = 0; j < 4; ++j) {
            int col = bn + tx * 4 + j;
            float v = acc[i][j] * scale + (bias ? bias[col] : 0.0f);
            if (ACT == 1) v = fmaxf(v, 0.0f);
            C[(size_t)row * N + col] = v;
        }
    }
}

// ---------------------------------------------------------------------------
// S[b,d,:] = sum_{src != d} elu( w(src,d) * (P[b,d,:] + Q[b,src,:]) + b1 )
// One block per (b,d). 256 threads, 2 channels each (2H = 512).
// Edge id for (src=i -> dst=d): e = i*63 + (d<i ? d : d-1); w = max over K=2.
// ---------------------------------------------------------------------------
__global__ __launch_bounds__(256) void edge_agg_kernel(
    const float* __restrict__ P, const float* __restrict__ Q,
    const float* __restrict__ edges, const float* __restrict__ b1,
    float* __restrict__ S)
{
    const int blk = blockIdx.x;   // b*64 + d
    const int d = blk & 63;
    const int b = blk >> 6;
    const int tid = threadIdx.x;

    const float p0 = P[(size_t)blk * 512 + tid];
    const float p1 = P[(size_t)blk * 512 + tid + 256];
    const float bb0 = b1[tid];
    const float bb1 = b1[tid + 256];
    const float* Qb = Q + (size_t)b * NN * 512;

    float acc0 = 0.f, acc1 = 0.f;
    for (int src = 0; src < NN; ++src) {
        if (src == d) continue;
        int e = src * 63 + (d < src ? d : d - 1);
        float w = fmaxf(edges[2 * e], edges[2 * e + 1]);
        float q0 = Qb[(size_t)src * 512 + tid];
        float q1 = Qb[(size_t)src * 512 + tid + 256];
        float v0 = w * (p0 + q0) + bb0;
        float v1 = w * (p1 + q1) + bb1;
        acc0 += (v0 > 0.f) ? v0 : expm1f(v0);
        acc1 += (v1 > 0.f) ? v1 : expm1f(v1);
    }
    S[(size_t)blk * 512 + tid] = acc0;
    S[(size_t)blk * 512 + tid + 256] = acc1;
}

// ---------------------------------------------------------------------------
// Fused GRU gates + new_hidden. One block per row (b*N+n), 256 threads (=H).
// r = sig(inputs@ir_w + ir_b + Gr); i = sig(inputs@ii_w + ii_b + Gi)
// n = tanh(inputs@in_w + in_b + r*Gn); NH = (1-i)*n + i*hidden
// ---------------------------------------------------------------------------
__global__ __launch_bounds__(256) void gru_kernel(
    const float* __restrict__ inputs, const float* __restrict__ hidden,
    const float* __restrict__ Gr, const float* __restrict__ Gi,
    const float* __restrict__ Gn,
    const float* __restrict__ ir_w, const float* __restrict__ ir_b,
    const float* __restrict__ ii_w, const float* __restrict__ ii_b,
    const float* __restrict__ in_w, const float* __restrict__ in_b,
    float* __restrict__ NH)
{
    const int row = blockIdx.x;
    const int h = threadIdx.x;
    const float* inr = inputs + (size_t)row * FF;

    float xr = ir_b[h], xi = ii_b[h], xn = in_b[h];
#pragma unroll
    for (int f = 0; f < FF; ++f) {
        float x = inr[f];
        xr += x * ir_w[f * HH + h];
        xi += x * ii_w[f * HH + h];
        xn += x * in_w[f * HH + h];
    }
    size_t o = (size_t)row * HH + h;
    float r  = 1.f / (1.f + expf(-(xr + Gr[o])));
    float ig = 1.f / (1.f + expf(-(xi + Gi[o])));
    float n  = tanhf(xn + r * Gn[o]);
    NH[o] = (1.f - ig) * n + ig * hidden[o];
}

// ---------------------------------------------------------------------------
// pred[row,f] = inputs[row,f] + H2[row,:] @ f3_w[:,f] + f3_b[f]
// ---------------------------------------------------------------------------
__global__ __launch_bounds__(256) void pred_kernel(
    const float* __restrict__ inputs, const float* __restrict__ H2,
    const float* __restrict__ f3_w, const float* __restrict__ f3_b,
    float* __restrict__ pred)
{
    const int idx = blockIdx.x * 256 + threadIdx.x;  // 0 .. 32767
    const int row = idx >> 3;
    const int f = idx & 7;
    const float* hr = H2 + (size_t)row * HH;
    float acc = f3_b[f];
    for (int k = 0; k < HH; ++k) acc += hr[k] * f3_w[k * FF + f];
    pred[idx] = inputs[idx] + acc;
}

// ---------------------------------------------------------------------------
extern "C" void kernel_launch(void* const* d_in, const int* in_sizes, int n_in,
                              void* d_out, int out_size, void* d_ws, size_t ws_size,
                              hipStream_t stream) {
    const float* inputs = (const float*)d_in[0];   // (B,N,F)
    const float* hidden = (const float*)d_in[1];   // (B,N,H)
    const float* edges  = (const float*)d_in[2];   // (E,2)
    // d_in[3] = edge_index (analytic, unused)
    const float* ed_w1 = (const float*)d_in[4];    // (512,512)
    const float* ed_b1 = (const float*)d_in[5];    // (512,)
    const float* ed_w2 = (const float*)d_in[6];    // (512,256)
    const float* ed_b2 = (const float*)d_in[7];    // (256,)
    const float* wr = (const float*)d_in[8];
    const float* wi = (const float*)d_in[9];
    const float* wh = (const float*)d_in[10];
    const float* ir_w = (const float*)d_in[11];
    const float* ir_b = (const float*)d_in[12];
    const float* ii_w = (const float*)d_in[13];
    const float* ii_b = (const float*)d_in[14];
    const float* in_w = (const float*)d_in[15];
    const float* in_b = (const float*)d_in[16];
    const float* f1_w = (const float*)d_in[17];
    const float* f1_b = (const float*)d_in[18];
    const float* f2_w = (const float*)d_in[19];
    const float* f2_b = (const float*)d_in[20];
    const float* f3_w = (const float*)d_in[21];
    const float* f3_b = (const float*)d_in[22];

    float* out = (float*)d_out;
    float* pred = out;                      // (B*N*F) = 32768
    float* NH = out + (size_t)BB * NN * FF; // (B*N*H) = 1048576

    const int R = BB * NN;       // 4096 rows
    float* ws = (float*)d_ws;
    // workspace layout (floats), with reuse:
    float* P   = ws + 0;                 // 4096*512
    float* Q   = ws + 2097152;           // 4096*512
    float* S   = ws + 4194304;           // 4096*512
    float* AGG = ws + 6291456;           // 4096*256
    float* GR  = ws + 0;                 // reuse P   (4096*256)
    float* GI  = ws + 1048576;           //           (4096*256)
    float* GN  = ws + 2097152;           // reuse Q   (4096*256)
    float* H1  = ws + 3145728;           //           (4096*256)
    float* H2  = ws + 4194304;           // reuse S   (4096*256)

    dim3 blk(256);

    // P = hidden @ ed_w1[0:256,:]   (4096,256)@(256,512)
    gemm_kernel<0><<<dim3(512 / 64, R / 64), blk, 0, stream>>>(
        hidden, ed_w1, nullptr, P, R, 512, 256, 1.0f);
    // Q = hidden @ ed_w1[256:512,:]
    gemm_kernel<0><<<dim3(512 / 64, R / 64), blk, 0, stream>>>(
        hidden, ed_w1 + (size_t)256 * 512, nullptr, Q, R, 512, 256, 1.0f);

    // S: per (b,d) elu-sum over 63 src
    edge_agg_kernel<<<dim3(R), blk, 0, stream>>>(P, Q, edges, ed_b1, S);

    // agg = S @ ed_w2 / 63 + ed_b2   (4096,512)@(512,256)
    gemm_kernel<0><<<dim3(256 / 64, R / 64), blk, 0, stream>>>(
        S, ed_w2, ed_b2, AGG, R, 256, 512, 1.0f / 63.0f);

    // GRU gate GEMMs (no bias)
    gemm_kernel<0><<<dim3(256 / 64, R / 64), blk, 0, stream>>>(
        AGG, wr, nullptr, GR, R, 256, 256, 1.0f);
    gemm_kernel<0><<<dim3(256 / 64, R / 64), blk, 0, stream>>>(
        AGG, wi, nullptr, GI, R, 256, 256, 1.0f);
    gemm_kernel<0><<<dim3(256 / 64, R / 64), blk, 0, stream>>>(
        AGG, wh, nullptr, GN, R, 256, 256, 1.0f);

    // fused GRU -> new_hidden (written directly into d_out)
    gru_kernel<<<dim3(R), blk, 0, stream>>>(
        inputs, hidden, GR, GI, GN,
        ir_w, ir_b, ii_w, ii_b, in_w, in_b, NH);

    // final MLP
    gemm_kernel<1><<<dim3(256 / 64, R / 64), blk, 0, stream>>>(
        NH, f1_w, f1_b, H1, R, 256, 256, 1.0f);
    gemm_kernel<1><<<dim3(256 / 64, R / 64), blk, 0, stream>>>(
        H1, f2_w, f2_b, H2, R, 256, 256, 1.0f);
    pred_kernel<<<dim3(BB * NN * FF / 256), blk, 0, stream>>>(
        inputs, H2, f3_w, f3_b, pred);
}

// Round 2
// 112.842 us; speedup vs baseline: 2.2907x; 2.2907x over previous
//
#include <hip/hip_runtime.h>
#include <hip/hip_bf16.h>
#include <math.h>

#define BB 64
#define NN 64
#define HH 256
#define FF 8

typedef __bf16 bf16;
typedef bf16 bf16x4 __attribute__((ext_vector_type(4)));
typedef bf16 bf16x8 __attribute__((ext_vector_type(8)));
typedef float f32x4 __attribute__((ext_vector_type(4)));

// async global->LDS, 16B per lane, wave-uniform LDS base + lane*16
#define GLL(g, l) __builtin_amdgcn_global_load_lds( \
    (const __attribute__((address_space(1))) void*)(g), \
    (__attribute__((address_space(3))) void*)(l), 16, 0, 0)

// ---------------------------------------------------------------------------
// Pack kernel: convert hidden + all GEMM weights to bf16; weights transposed
// to [N][K] so A- and B-fragments share the same LDS addressing.
// Regions (element counts):
//   hbf 1048576 | W1t 262144 ([1024][256]) | W2t 131072 ([256][512])
//   Wg 196608 ([3][256][256]) | f1t 65536 | f2t 65536   => total 1769472
// ---------------------------------------------------------------------------
__global__ __launch_bounds__(256) void pack_kernel(
    const float* __restrict__ hidden,
    const float* __restrict__ ed_w1, const float* __restrict__ ed_w2,
    const float* __restrict__ wr, const float* __restrict__ wi,
    const float* __restrict__ wh,
    const float* __restrict__ f1_w, const float* __restrict__ f2_w,
    bf16* __restrict__ hbf, bf16* __restrict__ W1t, bf16* __restrict__ W2t,
    bf16* __restrict__ Wg, bf16* __restrict__ f1t, bf16* __restrict__ f2t)
{
    int idx = blockIdx.x * 256 + threadIdx.x;
    if (idx < 1048576) { hbf[idx] = (bf16)hidden[idx]; return; }
    idx -= 1048576;
    if (idx < 262144) {
        int n = idx >> 8, k = idx & 255;
        W1t[idx] = (bf16)ed_w1[(n < 512 ? k : k + 256) * 512 + (n & 511)];
        return;
    }
    idx -= 262144;
    if (idx < 131072) {
        int n = idx >> 9, k = idx & 511;
        W2t[idx] = (bf16)ed_w2[k * 256 + n];
        return;
    }
    idx -= 131072;
    if (idx < 196608) {
        int g = idx >> 16, r = idx & 65535;
        int n = r >> 8, k = r & 255;
        const float* w = (g == 0) ? wr : ((g == 1) ? wi : wh);
        Wg[idx] = (bf16)w[k * 256 + n];
        return;
    }
    idx -= 196608;
    if (idx < 65536) {
        int n = idx >> 8, k = idx & 255;
        f1t[idx] = (bf16)f1_w[k * 256 + n];
        return;
    }
    idx -= 65536;
    {
        int n = idx >> 8, k = idx & 255;
        f2t[idx] = (bf16)f2_w[k * 256 + n];
    }
}

// ---------------------------------------------------------------------------
// MFMA GEMM, tile 64x64, 4 waves (2x2) of 32x32, BK=64, double-buffered LDS.
// A: [M=4096][K] bf16 row-major. Bt: [N][K] bf16 (pre-transposed weights).
// MODE 0: Cb = bf16(A@B)                         (G1: PQ)
// MODE 1: Cb = bf16(A@B * scale + bias)          (G2: agg)
// MODE 2: Cb = bf16(relu(A@B + bias))            (f1, f2)
// MODE 3: 3 B-matrices (wr,wi,wh) + fused GRU -> Cf=NH fp32, Cb=NH bf16
// ---------------------------------------------------------------------------
template<int MODE>
__global__ __launch_bounds__(256) void mfma_gemm(
    const bf16* __restrict__ A, const bf16* __restrict__ Bt,
    const float* __restrict__ bias,
    float* __restrict__ Cf, bf16* __restrict__ Cb,
    int N, int K, float scale,
    const float* __restrict__ inputs, const float* __restrict__ hidden,
    const float* __restrict__ irw, const float* __restrict__ irb,
    const float* __restrict__ iiw, const float* __restrict__ iib,
    const float* __restrict__ inw, const float* __restrict__ inb)
{
    constexpr int NB  = (MODE == 3) ? 3 : 1;
    constexpr int ASZ = 64 * 64 * 2;       // 8192 B per A tile
    constexpr int BSZ = ASZ * NB;
    __shared__ __align__(1024) char smem[2 * (ASZ + BSZ)];

    const int tid  = threadIdx.x;
    const int wave = tid >> 6, lane = tid & 63;
    const int wr_  = wave >> 1, wc_ = wave & 1;
    const int l15  = lane & 15, l4 = lane >> 4;
    const int bm   = blockIdx.y * 64, bn = blockIdx.x * 64;

    // staging constants: seg = 1KB = 8 rows x 64 cols(bf16); swizzled source col
    const int srow = lane >> 3;                            // row within segment
    const int scol = ((lane & 7) ^ (lane >> 3)) * 8;       // element col (inv-swz)

    f32x4 acc[NB][2][2];
#pragma unroll
    for (int g = 0; g < NB; ++g)
#pragma unroll
        for (int mf = 0; mf < 2; ++mf)
#pragma unroll
            for (int nf = 0; nf < 2; ++nf)
                acc[g][mf][nf] = (f32x4){0.f, 0.f, 0.f, 0.f};

    const int per = (8 * (1 + NB)) / 4;   // segments per wave

    auto stage = [&](int buf, int kt) {
        char* base = smem + buf * (ASZ + BSZ);
#pragma unroll
        for (int si = 0; si < per; ++si) {
            int s = wave * per + si;
            char* ldst = base + s * 1024 + lane * 16;
            const bf16* g;
            if (s < 8) {
                g = A + ((size_t)(bm + s * 8 + srow) * K + kt * 64 + scol);
            } else {
                int sb = s - 8;
                int gi = sb >> 3;      // which B matrix (MODE3)
                int r8 = sb & 7;
                g = Bt + (size_t)gi * 256 * 256
                      + (size_t)(bn + r8 * 8 + srow) * K + kt * 64 + scol;
            }
            GLL(g, ldst);
        }
    };

    auto compute = [&](int buf) {
        char* base = smem + buf * (ASZ + BSZ);
#pragma unroll
        for (int kk = 0; kk < 2; ++kk) {
            bf16x8 af[2];
#pragma unroll
            for (int mf = 0; mf < 2; ++mf) {
                int row = wr_ * 32 + mf * 16 + l15;
                int c0 = row * 128 + kk * 64 + l4 * 8;
                int sw = (row & 7) << 4;
                bf16x4 lo = *(const bf16x4*)(base + (c0 ^ sw));
                bf16x4 hi = *(const bf16x4*)(base + ((c0 + 32) ^ sw));
                af[mf] = __builtin_shufflevector(lo, hi, 0, 1, 2, 3, 4, 5, 6, 7);
            }
            bf16x8 bfr[NB][2];
#pragma unroll
            for (int g = 0; g < NB; ++g)
#pragma unroll
                for (int nf = 0; nf < 2; ++nf) {
                    int row = wc_ * 32 + nf * 16 + l15;
                    int c0 = row * 128 + kk * 64 + l4 * 8;
                    int sw = (row & 7) << 4;
                    const char* bb = base + ASZ + g * 8192;
                    bf16x4 lo = *(const bf16x4*)(bb + (c0 ^ sw));
                    bf16x4 hi = *(const bf16x4*)(bb + ((c0 + 32) ^ sw));
                    bfr[g][nf] = __builtin_shufflevector(lo, hi, 0, 1, 2, 3, 4, 5, 6, 7);
                }
#pragma unroll
            for (int g = 0; g < NB; ++g)
#pragma unroll
                for (int mf = 0; mf < 2; ++mf)
#pragma unroll
                    for (int nf = 0; nf < 2; ++nf)
                        acc[g][mf][nf] = __builtin_amdgcn_mfma_f32_16x16x32_bf16(
                            af[mf], bfr[g][nf], acc[g][mf][nf], 0, 0, 0);
        }
    };

    const int nt = K / 64;
    stage(0, 0);
    __syncthreads();
    for (int t = 0; t < nt; ++t) {
        if (t + 1 < nt) stage((t + 1) & 1, t + 1);
        compute(t & 1);
        __syncthreads();
    }

    if constexpr (MODE == 3) {
#pragma unroll
        for (int nf = 0; nf < 2; ++nf) {
            const int col = bn + wc_ * 32 + nf * 16 + l15;
            float w8r[8], w8i[8], w8n[8];
#pragma unroll
            for (int f = 0; f < 8; ++f) {
                w8r[f] = irw[f * 256 + col];
                w8i[f] = iiw[f * 256 + col];
                w8n[f] = inw[f * 256 + col];
            }
            const float xr0 = irb[col], xi0 = iib[col], xn0 = inb[col];
#pragma unroll
            for (int mf = 0; mf < 2; ++mf)
#pragma unroll
                for (int r = 0; r < 4; ++r) {
                    const int grow = bm + wr_ * 32 + mf * 16 + l4 * 4 + r;
                    const float* inp = inputs + (size_t)grow * 8;
                    float xr = xr0, xi = xi0, xn = xn0;
#pragma unroll
                    for (int f = 0; f < 8; ++f) {
                        float x = inp[f];
                        xr += x * w8r[f]; xi += x * w8i[f]; xn += x * w8n[f];
                    }
                    float aR = acc[0][mf][nf][r];
                    float aI = acc[1][mf][nf][r];
                    float aN = acc[2][mf][nf][r];
                    float rg = __builtin_amdgcn_rcpf(1.f + __expf(-(xr + aR)));
                    float ig = __builtin_amdgcn_rcpf(1.f + __expf(-(xi + aI)));
                    float tz = xn + rg * aN;
                    tz = fminf(fmaxf(tz, -15.f), 15.f);
                    float e2x = __expf(2.f * tz);
                    float nn = (e2x - 1.f) * __builtin_amdgcn_rcpf(e2x + 1.f);
                    size_t o = (size_t)grow * 256 + col;
                    float nh = (1.f - ig) * nn + ig * hidden[o];
                    Cf[o] = nh;
                    Cb[o] = (bf16)nh;
                }
        }
    } else {
#pragma unroll
        for (int mf = 0; mf < 2; ++mf)
#pragma unroll
            for (int nf = 0; nf < 2; ++nf)
#pragma unroll
                for (int r = 0; r < 4; ++r) {
                    int grow = bm + wr_ * 32 + mf * 16 + l4 * 4 + r;
                    int col = bn + wc_ * 32 + nf * 16 + l15;
                    float v = acc[0][mf][nf][r];
                    if constexpr (MODE == 1) v = v * scale + bias[col];
                    if constexpr (MODE == 2) v = fmaxf(v + bias[col], 0.f);
                    Cb[(size_t)grow * N + col] = (bf16)v;
                }
    }
}

// ---------------------------------------------------------------------------
// Edge aggregation: S[b,d,:] = sum_{src!=d} elu( w(src,d)*(P[b,d,:]+Q[b,src,:]) + b1 )
// PQ bf16 [4096][1024] (P = cols 0..511, Q = cols 512..1023). 4 dst per block.
// ---------------------------------------------------------------------------
__global__ __launch_bounds__(256) void edge_agg_kernel(
    const bf16* __restrict__ PQ, const float* __restrict__ edges,
    const float* __restrict__ b1, bf16* __restrict__ S)
{
    const int blk = blockIdx.x;
    const int b = blk >> 4;
    const int d0 = (blk & 15) * 4;
    const int t2 = threadIdx.x * 2;

    float p[4][2];
#pragma unroll
    for (int dd = 0; dd < 4; ++dd) {
        const bf16* row = PQ + (size_t)(b * 64 + d0 + dd) * 1024;
        p[dd][0] = (float)row[t2];
        p[dd][1] = (float)row[t2 + 1];
    }
    const float bb0 = b1[t2], bb1 = b1[t2 + 1];
    const bf16* Qb = PQ + (size_t)b * 64 * 1024 + 512;

    float acc[4][2];
#pragma unroll
    for (int dd = 0; dd < 4; ++dd) { acc[dd][0] = 0.f; acc[dd][1] = 0.f; }

    for (int src = 0; src < 64; ++src) {
        float q0 = (float)Qb[(size_t)src * 1024 + t2];
        float q1 = (float)Qb[(size_t)src * 1024 + t2 + 1];
        const float* ew = edges + 2 * (src * 63);
#pragma unroll
        for (int dd = 0; dd < 4; ++dd) {
            int d = d0 + dd;
            if (src == d) continue;
            int e2 = 2 * (d < src ? d : d - 1);
            float w = fmaxf(ew[e2], ew[e2 + 1]);
            float v0 = w * (p[dd][0] + q0) + bb0;
            float v1 = w * (p[dd][1] + q1) + bb1;
            acc[dd][0] += (v0 > 0.f) ? v0 : (__expf(v0) - 1.f);
            acc[dd][1] += (v1 > 0.f) ? v1 : (__expf(v1) - 1.f);
        }
    }
#pragma unroll
    for (int dd = 0; dd < 4; ++dd) {
        size_t o = (size_t)(b * 64 + d0 + dd) * 512 + t2;
        S[o] = (bf16)acc[dd][0];
        S[o + 1] = (bf16)acc[dd][1];
    }
}

// ---------------------------------------------------------------------------
// pred[row,f] = inputs[row,f] + H2[row,:] @ f3_w[:,f] + f3_b[f]
// ---------------------------------------------------------------------------
__global__ __launch_bounds__(256) void pred_kernel(
    const float* __restrict__ inputs, const bf16* __restrict__ H2,
    const float* __restrict__ f3_w, const float* __restrict__ f3_b,
    float* __restrict__ pred)
{
    const int idx = blockIdx.x * 256 + threadIdx.x;
    const int row = idx >> 3, f = idx & 7;
    const bf16* hr = H2 + (size_t)row * 256;
    float a = f3_b[f];
    for (int k = 0; k < 256; ++k) a += (float)hr[k] * f3_w[k * 8 + f];
    pred[idx] = inputs[idx] + a;
}

// ---------------------------------------------------------------------------
extern "C" void kernel_launch(void* const* d_in, const int* in_sizes, int n_in,
                              void* d_out, int out_size, void* d_ws, size_t ws_size,
                              hipStream_t stream) {
    const float* inputs = (const float*)d_in[0];
    const float* hidden = (const float*)d_in[1];
    const float* edges  = (const float*)d_in[2];
    const float* ed_w1 = (const float*)d_in[4];
    const float* ed_b1 = (const float*)d_in[5];
    const float* ed_w2 = (const float*)d_in[6];
    const float* ed_b2 = (const float*)d_in[7];
    const float* wr = (const float*)d_in[8];
    const float* wi = (const float*)d_in[9];
    const float* wh = (const float*)d_in[10];
    const float* ir_w = (const float*)d_in[11];
    const float* ir_b = (const float*)d_in[12];
    const float* ii_w = (const float*)d_in[13];
    const float* ii_b = (const float*)d_in[14];
    const float* in_w = (const float*)d_in[15];
    const float* in_b = (const float*)d_in[16];
    const float* f1_w = (const float*)d_in[17];
    const float* f1_b = (const float*)d_in[18];
    const float* f2_w = (const float*)d_in[19];
    const float* f2_b = (const float*)d_in[20];
    const float* f3_w = (const float*)d_in[21];
    const float* f3_b = (const float*)d_in[22];

    float* out = (float*)d_out;
    float* pred = out;
    float* NH = out + (size_t)BB * NN * FF;

    // bf16 workspace layout (element offsets)
    bf16* bws = (bf16*)d_ws;
    bf16* PQ   = bws;              // 4096*1024
    bf16* Sb   = bws + 4194304;    // 4096*512
    bf16* AGGb = bws + 6291456;    // 4096*256
    bf16* NHb  = bws + 7340032;    // 4096*256
    bf16* H1b  = bws + 8388608;    // 4096*256
    bf16* H2b  = bws + 9437184;    // 4096*256
    bf16* hbf  = bws + 10485760;   // 4096*256
    bf16* W1t  = bws + 11534336;   // 1024*256
    bf16* W2t  = bws + 11796480;   // 256*512
    bf16* Wg   = bws + 11927552;   // 3*256*256
    bf16* f1t  = bws + 12124160;   // 256*256
    bf16* f2t  = bws + 12189696;   // 256*256

    dim3 blk(256);

    pack_kernel<<<dim3(6912), blk, 0, stream>>>(
        hidden, ed_w1, ed_w2, wr, wi, wh, f1_w, f2_w,
        hbf, W1t, W2t, Wg, f1t, f2t);

    // G1: PQ = hidden @ [W1top | W1bot]   (4096,1024,256)
    mfma_gemm<0><<<dim3(16, 64), blk, 0, stream>>>(
        hbf, W1t, nullptr, nullptr, PQ, 1024, 256, 1.f,
        nullptr, nullptr, nullptr, nullptr, nullptr, nullptr, nullptr, nullptr);

    // S: per-(b,d) elu-sum over 63 sources
    edge_agg_kernel<<<dim3(1024), blk, 0, stream>>>(PQ, edges, ed_b1, Sb);

    // G2: agg = S @ ed_w2 / 63 + ed_b2    (4096,256,512)
    mfma_gemm<1><<<dim3(4, 64), blk, 0, stream>>>(
        Sb, W2t, ed_b2, nullptr, AGGb, 256, 512, 1.f / 63.f,
        nullptr, nullptr, nullptr, nullptr, nullptr, nullptr, nullptr, nullptr);

    // G3: gates + fused GRU -> NH (fp32 out) + NHb (bf16)
    mfma_gemm<3><<<dim3(4, 64), blk, 0, stream>>>(
        AGGb, Wg, nullptr, NH, NHb, 256, 256, 1.f,
        inputs, hidden, ir_w, ir_b, ii_w, ii_b, in_w, in_b);

    // f1, f2 (relu)
    mfma_gemm<2><<<dim3(4, 64), blk, 0, stream>>>(
        NHb, f1t, f1_b, nullptr, H1b, 256, 256, 1.f,
        nullptr, nullptr, nullptr, nullptr, nullptr, nullptr, nullptr, nullptr);
    mfma_gemm<2><<<dim3(4, 64), blk, 0, stream>>>(
        H1b, f2t, f2_b, nullptr, H2b, 256, 256, 1.f,
        nullptr, nullptr, nullptr, nullptr, nullptr, nullptr, nullptr, nullptr);

    pred_kernel<<<dim3(128), blk, 0, stream>>>(inputs, H2b, f3_w, f3_b, pred);
}

// Round 4
// 83.162 us; speedup vs baseline: 3.1082x; 1.3569x over previous
//
#include <hip/hip_runtime.h>
#include <hip/hip_bf16.h>
#include <math.h>

#define BB 64
#define NN 64
#define HH 256
#define FF 8

typedef __bf16 bf16;
typedef bf16 bf16x4 __attribute__((ext_vector_type(4)));
typedef bf16 bf16x8 __attribute__((ext_vector_type(8)));
typedef float f32x4 __attribute__((ext_vector_type(4)));

// async global->LDS, 16B per lane, wave-uniform LDS base + lane*16
#define GLL(g, l) __builtin_amdgcn_global_load_lds( \
    (const __attribute__((address_space(1))) void*)(g), \
    (__attribute__((address_space(3))) void*)(l), 16, 0, 0)

// ---------------------------------------------------------------------------
// Pack kernel (round-2 proven): bf16 regions (element counts):
//   hbf 1048576 | W1t 262144 [1024][256] | W2t 131072 [256][512]
//   Wg 196608 [3][256][256] | f1t 65536 | f2t 65536   => total 1769472
// ---------------------------------------------------------------------------
__global__ __launch_bounds__(256) void pack_kernel(
    const float* __restrict__ hidden,
    const float* __restrict__ ed_w1, const float* __restrict__ ed_w2,
    const float* __restrict__ wr, const float* __restrict__ wi,
    const float* __restrict__ wh,
    const float* __restrict__ f1_w, const float* __restrict__ f2_w,
    bf16* __restrict__ hbf, bf16* __restrict__ W1t, bf16* __restrict__ W2t,
    bf16* __restrict__ Wg, bf16* __restrict__ f1t, bf16* __restrict__ f2t)
{
    int idx = blockIdx.x * 256 + threadIdx.x;
    if (idx < 1048576) { hbf[idx] = (bf16)hidden[idx]; return; }
    idx -= 1048576;
    if (idx < 262144) {
        int n = idx >> 8, k = idx & 255;
        W1t[idx] = (bf16)ed_w1[(n < 512 ? k : k + 256) * 512 + (n & 511)];
        return;
    }
    idx -= 262144;
    if (idx < 131072) {
        int n = idx >> 9, k = idx & 511;
        W2t[idx] = (bf16)ed_w2[k * 256 + n];
        return;
    }
    idx -= 131072;
    if (idx < 196608) {
        int g = idx >> 16, r = idx & 65535;
        int n = r >> 8, k = r & 255;
        const float* w = (g == 0) ? wr : ((g == 1) ? wi : wh);
        Wg[idx] = (bf16)w[k * 256 + n];
        return;
    }
    idx -= 196608;
    if (idx < 65536) {
        int n = idx >> 8, k = idx & 255;
        f1t[idx] = (bf16)f1_w[k * 256 + n];
        return;
    }
    idx -= 65536;
    {
        int n = idx >> 8, k = idx & 255;
        f2t[idx] = (bf16)f2_w[k * 256 + n];
    }
}

// ---------------------------------------------------------------------------
// MFMA GEMM, tile 64x64, 4 waves (2x2) of 32x32, BK=64, double-buffered LDS.
// A: [M][K] bf16 row-major. Bt: [N][K] bf16 (pre-transposed weights).
// MODE 0: Cb = bf16(A@B)
// MODE 1: Cb = bf16(A@B * scale + bias)
// MODE 2: Cb = bf16(relu(A@B + bias))
// MODE 3: 3 B-matrices (wr,wi,wh) + fused GRU -> Cf=NH fp32, Cb=NH bf16
// ---------------------------------------------------------------------------
template<int MODE>
__global__ __launch_bounds__(256) void mfma_gemm(
    const bf16* __restrict__ A, const bf16* __restrict__ Bt,
    const float* __restrict__ bias,
    float* __restrict__ Cf, bf16* __restrict__ Cb,
    int N, int K, float scale,
    const float* __restrict__ inputs, const float* __restrict__ hidden,
    const float* __restrict__ irw, const float* __restrict__ irb,
    const float* __restrict__ iiw, const float* __restrict__ iib,
    const float* __restrict__ inw, const float* __restrict__ inb)
{
    constexpr int NB  = (MODE == 3) ? 3 : 1;
    constexpr int ASZ = 64 * 64 * 2;
    constexpr int BSZ = ASZ * NB;
    __shared__ __align__(1024) char smem[2 * (ASZ + BSZ)];

    const int tid  = threadIdx.x;
    const int wave = tid >> 6, lane = tid & 63;
    const int wr_  = wave >> 1, wc_ = wave & 1;
    const int l15  = lane & 15, l4 = lane >> 4;
    const int bm   = blockIdx.y * 64, bn = blockIdx.x * 64;

    const int srow = lane >> 3;
    const int scol = ((lane & 7) ^ (lane >> 3)) * 8;

    f32x4 acc[NB][2][2];
#pragma unroll
    for (int g = 0; g < NB; ++g)
#pragma unroll
        for (int mf = 0; mf < 2; ++mf)
#pragma unroll
            for (int nf = 0; nf < 2; ++nf)
                acc[g][mf][nf] = (f32x4){0.f, 0.f, 0.f, 0.f};

    const int per = (8 * (1 + NB)) / 4;

    auto stage = [&](int buf, int kt) {
        char* base = smem + buf * (ASZ + BSZ);
#pragma unroll
        for (int si = 0; si < per; ++si) {
            int s = wave * per + si;
            char* ldst = base + s * 1024 + lane * 16;
            const bf16* g;
            if (s < 8) {
                g = A + ((size_t)(bm + s * 8 + srow) * K + kt * 64 + scol);
            } else {
                int sb = s - 8;
                int gi = sb >> 3;
                int r8 = sb & 7;
                g = Bt + (size_t)gi * 256 * K
                      + (size_t)(bn + r8 * 8 + srow) * K + kt * 64 + scol;
            }
            GLL(g, ldst);
        }
    };

    auto compute = [&](int buf) {
        char* base = smem + buf * (ASZ + BSZ);
#pragma unroll
        for (int kk = 0; kk < 2; ++kk) {
            bf16x8 af[2];
#pragma unroll
            for (int mf = 0; mf < 2; ++mf) {
                int row = wr_ * 32 + mf * 16 + l15;
                int c0 = row * 128 + kk * 64 + l4 * 8;
                int sw = (row & 7) << 4;
                bf16x4 lo = *(const bf16x4*)(base + (c0 ^ sw));
                bf16x4 hi = *(const bf16x4*)(base + ((c0 + 32) ^ sw));
                af[mf] = __builtin_shufflevector(lo, hi, 0, 1, 2, 3, 4, 5, 6, 7);
            }
            bf16x8 bfr[NB][2];
#pragma unroll
            for (int g = 0; g < NB; ++g)
#pragma unroll
                for (int nf = 0; nf < 2; ++nf) {
                    int row = wc_ * 32 + nf * 16 + l15;
                    int c0 = row * 128 + kk * 64 + l4 * 8;
                    int sw = (row & 7) << 4;
                    const char* bb = base + ASZ + g * 8192;
                    bf16x4 lo = *(const bf16x4*)(bb + (c0 ^ sw));
                    bf16x4 hi = *(const bf16x4*)(bb + ((c0 + 32) ^ sw));
                    bfr[g][nf] = __builtin_shufflevector(lo, hi, 0, 1, 2, 3, 4, 5, 6, 7);
                }
#pragma unroll
            for (int g = 0; g < NB; ++g)
#pragma unroll
                for (int mf = 0; mf < 2; ++mf)
#pragma unroll
                    for (int nf = 0; nf < 2; ++nf)
                        acc[g][mf][nf] = __builtin_amdgcn_mfma_f32_16x16x32_bf16(
                            af[mf], bfr[g][nf], acc[g][mf][nf], 0, 0, 0);
        }
    };

    const int nt = K / 64;
    stage(0, 0);
    __syncthreads();
    for (int t = 0; t < nt; ++t) {
        if (t + 1 < nt) stage((t + 1) & 1, t + 1);
        compute(t & 1);
        __syncthreads();
    }

    if constexpr (MODE == 3) {
#pragma unroll
        for (int nf = 0; nf < 2; ++nf) {
            const int col = bn + wc_ * 32 + nf * 16 + l15;
            float w8r[8], w8i[8], w8n[8];
#pragma unroll
            for (int f = 0; f < 8; ++f) {
                w8r[f] = irw[f * 256 + col];
                w8i[f] = iiw[f * 256 + col];
                w8n[f] = inw[f * 256 + col];
            }
            const float xr0 = irb[col], xi0 = iib[col], xn0 = inb[col];
#pragma unroll
            for (int mf = 0; mf < 2; ++mf)
#pragma unroll
                for (int r = 0; r < 4; ++r) {
                    const int grow = bm + wr_ * 32 + mf * 16 + l4 * 4 + r;
                    const float* inp = inputs + (size_t)grow * 8;
                    float xr = xr0, xi = xi0, xn = xn0;
#pragma unroll
                    for (int f = 0; f < 8; ++f) {
                        float x = inp[f];
                        xr += x * w8r[f]; xi += x * w8i[f]; xn += x * w8n[f];
                    }
                    float aR = acc[0][mf][nf][r];
                    float aI = acc[1][mf][nf][r];
                    float aN = acc[2][mf][nf][r];
                    float rg = __builtin_amdgcn_rcpf(1.f + __expf(-(xr + aR)));
                    float ig = __builtin_amdgcn_rcpf(1.f + __expf(-(xi + aI)));
                    float tz = xn + rg * aN;
                    tz = fminf(fmaxf(tz, -15.f), 15.f);
                    float e2x = __expf(2.f * tz);
                    float nn = (e2x - 1.f) * __builtin_amdgcn_rcpf(e2x + 1.f);
                    size_t o = (size_t)grow * 256 + col;
                    float nh = (1.f - ig) * nn + ig * hidden[o];
                    Cf[o] = nh;
                    Cb[o] = (bf16)nh;
                }
        }
    } else {
#pragma unroll
        for (int mf = 0; mf < 2; ++mf)
#pragma unroll
            for (int nf = 0; nf < 2; ++nf)
#pragma unroll
                for (int r = 0; r < 4; ++r) {
                    int grow = bm + wr_ * 32 + mf * 16 + l4 * 4 + r;
                    int col = bn + wc_ * 32 + nf * 16 + l15;
                    float v = acc[0][mf][nf][r];
                    if constexpr (MODE == 1) v = v * scale + bias[col];
                    if constexpr (MODE == 2) v = fmaxf(v + bias[col], 0.f);
                    Cb[(size_t)grow * N + col] = (bf16)v;
                }
    }
}

// ---------------------------------------------------------------------------
// Edge aggregation v3 (high-occupancy).
// Grid 2048: blk = b*32 + dgrp*2 + chh. 256 threads, 1 channel x 4 dst each.
// S[b,d,ch] = sum_{src} elu( w(src,d)*(P[b,d,ch]+Q[b,src,ch]) + b1[ch] )
//           - elu(b1[ch])   (self term src==d included with w=0, exact cancel)
// ---------------------------------------------------------------------------
__global__ __launch_bounds__(256) void edge_agg_kernel(
    const bf16* __restrict__ PQ, const float* __restrict__ edges,
    const float* __restrict__ b1, bf16* __restrict__ S)
{
    const int blk = blockIdx.x;
    const int chh = blk & 1;
    const int dgrp = (blk >> 1) & 15;
    const int b = blk >> 5;
    const int tid = threadIdx.x;
    const int ch = chh * 256 + tid;
    const int d0 = dgrp * 4;

    __shared__ __align__(16) float wls[64][4];
    {
        int src = tid >> 2, dd = tid & 3;
        int d = d0 + dd;
        float w = 0.f;
        if (src != d) {
            int e = src * 63 + (d < src ? d : d - 1);
            float2 ev = ((const float2*)edges)[e];
            w = fmaxf(ev.x, ev.y);
        }
        wls[src][dd] = w;
    }
    __syncthreads();

    const bf16* Pb = PQ + (size_t)(b * 64) * 1024;
    float p[4];
#pragma unroll
    for (int dd = 0; dd < 4; ++dd)
        p[dd] = (float)Pb[(size_t)(d0 + dd) * 1024 + ch];
    const float bb = b1[ch];
    const bf16* Qp = Pb + 512 + ch;

    float acc[4] = {0.f, 0.f, 0.f, 0.f};
#pragma unroll 4
    for (int src = 0; src < 64; ++src) {
        float q = (float)Qp[(size_t)src * 1024];
        float4 wv = *(const float4*)&wls[src][0];
        float w[4] = {wv.x, wv.y, wv.z, wv.w};
#pragma unroll
        for (int dd = 0; dd < 4; ++dd) {
            float v = w[dd] * (p[dd] + q) + bb;
            float e = __expf(v) - 1.f;
            acc[dd] += (v > 0.f) ? v : e;
        }
    }
    const float selfc = (bb > 0.f) ? bb : (__expf(bb) - 1.f);
#pragma unroll
    for (int dd = 0; dd < 4; ++dd) {
        size_t o = (size_t)(b * 64 + d0 + dd) * 512 + ch;
        S[o] = (bf16)(acc[dd] - selfc);
    }
}

// ---------------------------------------------------------------------------
// pred[row,f] = inputs[row,f] + H2[row,:] @ f3_w[:,f] + f3_b[f]
// f3_w staged in LDS; H2 row read as bf16x8.
// ---------------------------------------------------------------------------
__global__ __launch_bounds__(256) void pred_kernel(
    const float* __restrict__ inputs, const bf16* __restrict__ H2,
    const float* __restrict__ f3_w, const float* __restrict__ f3_b,
    float* __restrict__ pred)
{
    __shared__ float f3s[2048];
    for (int i = threadIdx.x; i < 2048; i += 256) f3s[i] = f3_w[i];
    __syncthreads();

    const int idx = blockIdx.x * 256 + threadIdx.x;
    const int row = idx >> 3, f = idx & 7;
    const bf16* hr = H2 + (size_t)row * 256;
    float a = f3_b[f];
    for (int k0 = 0; k0 < 256; k0 += 8) {
        bf16x8 h8 = *(const bf16x8*)(hr + k0);
#pragma unroll
        for (int j = 0; j < 8; ++j)
            a += (float)h8[j] * f3s[(k0 + j) * 8 + f];
    }
    pred[idx] = inputs[idx] + a;
}

// ---------------------------------------------------------------------------
extern "C" void kernel_launch(void* const* d_in, const int* in_sizes, int n_in,
                              void* d_out, int out_size, void* d_ws, size_t ws_size,
                              hipStream_t stream) {
    const float* inputs = (const float*)d_in[0];
    const float* hidden = (const float*)d_in[1];
    const float* edges  = (const float*)d_in[2];
    const float* ed_w1 = (const float*)d_in[4];
    const float* ed_b1 = (const float*)d_in[5];
    const float* ed_w2 = (const float*)d_in[6];
    const float* ed_b2 = (const float*)d_in[7];
    const float* wr = (const float*)d_in[8];
    const float* wi = (const float*)d_in[9];
    const float* wh = (const float*)d_in[10];
    const float* ir_w = (const float*)d_in[11];
    const float* ir_b = (const float*)d_in[12];
    const float* ii_w = (const float*)d_in[13];
    const float* ii_b = (const float*)d_in[14];
    const float* in_w = (const float*)d_in[15];
    const float* in_b = (const float*)d_in[16];
    const float* f1_w = (const float*)d_in[17];
    const float* f1_b = (const float*)d_in[18];
    const float* f2_w = (const float*)d_in[19];
    const float* f2_b = (const float*)d_in[20];
    const float* f3_w = (const float*)d_in[21];
    const float* f3_b = (const float*)d_in[22];

    float* out = (float*)d_out;
    float* pred = out;
    float* NH = out + (size_t)BB * NN * FF;

    // bf16 workspace layout (element offsets) — round-2 proven
    bf16* bws = (bf16*)d_ws;
    bf16* PQ   = bws;              // 4096*1024
    bf16* Sb   = bws + 4194304;    // 4096*512
    bf16* AGGb = bws + 6291456;    // 4096*256
    bf16* NHb  = bws + 7340032;    // 4096*256
    bf16* H1b  = bws + 8388608;    // 4096*256
    bf16* H2b  = bws + 9437184;    // 4096*256
    bf16* hbf  = bws + 10485760;   // 4096*256
    bf16* W1t  = bws + 11534336;   // 1024*256
    bf16* W2t  = bws + 11796480;   // 256*512
    bf16* Wg   = bws + 11927552;   // 3*256*256
    bf16* f1t  = bws + 12124160;   // 256*256
    bf16* f2t  = bws + 12189696;   // 256*256

    dim3 blk(256);

    pack_kernel<<<dim3(6912), blk, 0, stream>>>(
        hidden, ed_w1, ed_w2, wr, wi, wh, f1_w, f2_w,
        hbf, W1t, W2t, Wg, f1t, f2t);

    // G1: PQ = hidden @ [W1top | W1bot]   (4096,1024,256)
    mfma_gemm<0><<<dim3(16, 64), blk, 0, stream>>>(
        hbf, W1t, nullptr, nullptr, PQ, 1024, 256, 1.f,
        nullptr, nullptr, nullptr, nullptr, nullptr, nullptr, nullptr, nullptr);

    // S: per-(b,d) elu-sum over sources (high-occupancy)
    edge_agg_kernel<<<dim3(2048), blk, 0, stream>>>(PQ, edges, ed_b1, Sb);

    // G2: agg = S @ ed_w2 / 63 + ed_b2    (4096,256,512)
    mfma_gemm<1><<<dim3(4, 64), blk, 0, stream>>>(
        Sb, W2t, ed_b2, nullptr, AGGb, 256, 512, 1.f / 63.f,
        nullptr, nullptr, nullptr, nullptr, nullptr, nullptr, nullptr, nullptr);

    // G3: gates + fused GRU -> NH (fp32 out) + NHb (bf16)
    mfma_gemm<3><<<dim3(4, 64), blk, 0, stream>>>(
        AGGb, Wg, nullptr, NH, NHb, 256, 256, 1.f,
        inputs, hidden, ir_w, ir_b, ii_w, ii_b, in_w, in_b);

    // f1, f2 (relu)
    mfma_gemm<2><<<dim3(4, 64), blk, 0, stream>>>(
        NHb, f1t, f1_b, nullptr, H1b, 256, 256, 1.f,
        nullptr, nullptr, nullptr, nullptr, nullptr, nullptr, nullptr, nullptr);
    mfma_gemm<2><<<dim3(4, 64), blk, 0, stream>>>(
        H1b, f2t, f2_b, nullptr, H2b, 256, 256, 1.f,
        nullptr, nullptr, nullptr, nullptr, nullptr, nullptr, nullptr, nullptr);

    pred_kernel<<<dim3(128), blk, 0, stream>>>(inputs, H2b, f3_w, f3_b, pred);
}

// Round 5
// 82.174 us; speedup vs baseline: 3.1456x; 1.0120x over previous
//
#include <hip/hip_runtime.h>
#include <hip/hip_bf16.h>
#include <math.h>

#define BB 64
#define NN 64
#define HH 256
#define FF 8

typedef __bf16 bf16;
typedef bf16 bf16x2 __attribute__((ext_vector_type(2)));
typedef bf16 bf16x4 __attribute__((ext_vector_type(4)));
typedef bf16 bf16x8 __attribute__((ext_vector_type(8)));
typedef float f32x2 __attribute__((ext_vector_type(2)));
typedef float f32x4 __attribute__((ext_vector_type(4)));

// async global->LDS, 16B per lane, wave-uniform LDS base + lane*16
#define GLL(g, l) __builtin_amdgcn_global_load_lds( \
    (const __attribute__((address_space(1))) void*)(g), \
    (__attribute__((address_space(3))) void*)(l), 16, 0, 0)

__device__ __forceinline__ f32x2 unpk(unsigned int u) {
    union { unsigned int i; float f; } a, b;
    a.i = (u & 0xffffu) << 16;
    b.i = u & 0xffff0000u;
    f32x2 r; r.x = a.f; r.y = b.f; return r;
}

// ---------------------------------------------------------------------------
// Pack kernel v2: LDS-tiled transposes (coalesced both sides) + hbf convert.
// Blocks 0..175: weight transposes, dst[n*R + k] = src[k*C + n]
//   0..63  : ed_w1 halves -> W1t   (R=256, C=512), 32 tiles each
//   64..95 : ed_w2        -> W2t   (R=512, C=256)
//   96..175: wr,wi,wh,f1_w,f2_w -> Wg(3), f1t, f2t (R=C=256), 16 tiles each
// Blocks 176..1199: hbf = bf16(hidden), float4 -> bf16x4 coalesced.
// ---------------------------------------------------------------------------
__global__ __launch_bounds__(256) void pack_kernel(
    const float* __restrict__ hidden,
    const float* __restrict__ ed_w1, const float* __restrict__ ed_w2,
    const float* __restrict__ wr, const float* __restrict__ wi,
    const float* __restrict__ wh,
    const float* __restrict__ f1_w, const float* __restrict__ f2_w,
    bf16* __restrict__ hbf, bf16* __restrict__ W1t, bf16* __restrict__ W2t,
    bf16* __restrict__ Wg, bf16* __restrict__ f1t, bf16* __restrict__ f2t)
{
    const int t = blockIdx.x;
    const int tid = threadIdx.x;

    if (t >= 176) {  // hbf convert
        int i = (t - 176) * 1024 + tid * 4;
        float4 v = *(const float4*)(hidden + i);
        bf16x4 o;
        o[0] = (bf16)v.x; o[1] = (bf16)v.y; o[2] = (bf16)v.z; o[3] = (bf16)v.w;
        *(bf16x4*)(hbf + i) = o;
        return;
    }

    const float* src; bf16* dst; int R, C, tile;
    if (t < 64) {
        src = ed_w1 + (t >= 32 ? 131072 : 0);
        dst = W1t + (t >= 32 ? 131072 : 0);
        R = 256; C = 512; tile = t & 31;
    } else if (t < 96) {
        src = ed_w2; dst = W2t; R = 512; C = 256; tile = t - 64;
    } else {
        int m = (t - 96) >> 4; tile = (t - 96) & 15; R = 256; C = 256;
        const float* ss[5] = {wr, wi, wh, f1_w, f2_w};
        bf16* dd[5] = {Wg, Wg + 65536, Wg + 131072, f1t, f2t};
        src = ss[m]; dst = dd[m];
    }
    const int tc = C >> 6;
    const int k0 = (tile / tc) * 64, n0 = (tile % tc) * 64;

    __shared__ float ls[64][65];
    {
        int rr = tid >> 2, cc = (tid & 3) * 16;
        const float* sp = src + (size_t)(k0 + rr) * C + n0 + cc;
#pragma unroll
        for (int j = 0; j < 16; j += 4) {
            float4 v = *(const float4*)(sp + j);
            ls[rr][cc + j] = v.x; ls[rr][cc + j + 1] = v.y;
            ls[rr][cc + j + 2] = v.z; ls[rr][cc + j + 3] = v.w;
        }
    }
    __syncthreads();
    {
        int n = tid >> 2, kc = (tid & 3) * 16;
        bf16x8 o0, o1;
#pragma unroll
        for (int j = 0; j < 8; ++j) o0[j] = (bf16)ls[kc + j][n];
#pragma unroll
        for (int j = 0; j < 8; ++j) o1[j] = (bf16)ls[kc + 8 + j][n];
        bf16* dp = dst + (size_t)(n0 + n) * R + k0 + kc;
        *(bf16x8*)dp = o0;
        *(bf16x8*)(dp + 8) = o1;
    }
}

// ---------------------------------------------------------------------------
// MFMA GEMM, tile 64x64, 4 waves (2x2) of 32x32, BK=64, double-buffered LDS.
// A: [M][K] bf16 row-major. Bt: [N][K] bf16 (pre-transposed weights).
// MODE 0: Cb = bf16(A@B)
// MODE 1: Cb = bf16(A@B * scale + bias)
// MODE 2: Cb = bf16(relu(A@B + bias))
// MODE 3: 3 B-matrices (wr,wi,wh) + fused GRU -> Cf=NH fp32, Cb=NH bf16
// ---------------------------------------------------------------------------
template<int MODE>
__global__ __launch_bounds__(256) void mfma_gemm(
    const bf16* __restrict__ A, const bf16* __restrict__ Bt,
    const float* __restrict__ bias,
    float* __restrict__ Cf, bf16* __restrict__ Cb,
    int N, int K, float scale,
    const float* __restrict__ inputs, const float* __restrict__ hidden,
    const float* __restrict__ irw, const float* __restrict__ irb,
    const float* __restrict__ iiw, const float* __restrict__ iib,
    const float* __restrict__ inw, const float* __restrict__ inb)
{
    constexpr int NB  = (MODE == 3) ? 3 : 1;
    constexpr int ASZ = 64 * 64 * 2;
    constexpr int BSZ = ASZ * NB;
    __shared__ __align__(1024) char smem[2 * (ASZ + BSZ)];

    const int tid  = threadIdx.x;
    const int wave = tid >> 6, lane = tid & 63;
    const int wr_  = wave >> 1, wc_ = wave & 1;
    const int l15  = lane & 15, l4 = lane >> 4;
    const int bm   = blockIdx.y * 64, bn = blockIdx.x * 64;

    const int srow = lane >> 3;
    const int scol = ((lane & 7) ^ (lane >> 3)) * 8;

    f32x4 acc[NB][2][2];
#pragma unroll
    for (int g = 0; g < NB; ++g)
#pragma unroll
        for (int mf = 0; mf < 2; ++mf)
#pragma unroll
            for (int nf = 0; nf < 2; ++nf)
                acc[g][mf][nf] = (f32x4){0.f, 0.f, 0.f, 0.f};

    const int per = (8 * (1 + NB)) / 4;

    auto stage = [&](int buf, int kt) {
        char* base = smem + buf * (ASZ + BSZ);
#pragma unroll
        for (int si = 0; si < per; ++si) {
            int s = wave * per + si;
            char* ldst = base + s * 1024 + lane * 16;
            const bf16* g;
            if (s < 8) {
                g = A + ((size_t)(bm + s * 8 + srow) * K + kt * 64 + scol);
            } else {
                int sb = s - 8;
                int gi = sb >> 3;
                int r8 = sb & 7;
                g = Bt + (size_t)gi * 256 * K
                      + (size_t)(bn + r8 * 8 + srow) * K + kt * 64 + scol;
            }
            GLL(g, ldst);
        }
    };

    auto compute = [&](int buf) {
        char* base = smem + buf * (ASZ + BSZ);
#pragma unroll
        for (int kk = 0; kk < 2; ++kk) {
            bf16x8 af[2];
#pragma unroll
            for (int mf = 0; mf < 2; ++mf) {
                int row = wr_ * 32 + mf * 16 + l15;
                int c0 = row * 128 + kk * 64 + l4 * 8;
                int sw = (row & 7) << 4;
                bf16x4 lo = *(const bf16x4*)(base + (c0 ^ sw));
                bf16x4 hi = *(const bf16x4*)(base + ((c0 + 32) ^ sw));
                af[mf] = __builtin_shufflevector(lo, hi, 0, 1, 2, 3, 4, 5, 6, 7);
            }
            bf16x8 bfr[NB][2];
#pragma unroll
            for (int g = 0; g < NB; ++g)
#pragma unroll
                for (int nf = 0; nf < 2; ++nf) {
                    int row = wc_ * 32 + nf * 16 + l15;
                    int c0 = row * 128 + kk * 64 + l4 * 8;
                    int sw = (row & 7) << 4;
                    const char* bb = base + ASZ + g * 8192;
                    bf16x4 lo = *(const bf16x4*)(bb + (c0 ^ sw));
                    bf16x4 hi = *(const bf16x4*)(bb + ((c0 + 32) ^ sw));
                    bfr[g][nf] = __builtin_shufflevector(lo, hi, 0, 1, 2, 3, 4, 5, 6, 7);
                }
#pragma unroll
            for (int g = 0; g < NB; ++g)
#pragma unroll
                for (int mf = 0; mf < 2; ++mf)
#pragma unroll
                    for (int nf = 0; nf < 2; ++nf)
                        acc[g][mf][nf] = __builtin_amdgcn_mfma_f32_16x16x32_bf16(
                            af[mf], bfr[g][nf], acc[g][mf][nf], 0, 0, 0);
        }
    };

    const int nt = K / 64;
    stage(0, 0);
    __syncthreads();
    for (int t = 0; t < nt; ++t) {
        if (t + 1 < nt) stage((t + 1) & 1, t + 1);
        compute(t & 1);
        __syncthreads();
    }

    if constexpr (MODE == 3) {
#pragma unroll
        for (int nf = 0; nf < 2; ++nf) {
            const int col = bn + wc_ * 32 + nf * 16 + l15;
            float w8r[8], w8i[8], w8n[8];
#pragma unroll
            for (int f = 0; f < 8; ++f) {
                w8r[f] = irw[f * 256 + col];
                w8i[f] = iiw[f * 256 + col];
                w8n[f] = inw[f * 256 + col];
            }
            const float xr0 = irb[col], xi0 = iib[col], xn0 = inb[col];
#pragma unroll
            for (int mf = 0; mf < 2; ++mf)
#pragma unroll
                for (int r = 0; r < 4; ++r) {
                    const int grow = bm + wr_ * 32 + mf * 16 + l4 * 4 + r;
                    const float* inp = inputs + (size_t)grow * 8;
                    float xr = xr0, xi = xi0, xn = xn0;
#pragma unroll
                    for (int f = 0; f < 8; ++f) {
                        float x = inp[f];
                        xr += x * w8r[f]; xi += x * w8i[f]; xn += x * w8n[f];
                    }
                    float aR = acc[0][mf][nf][r];
                    float aI = acc[1][mf][nf][r];
                    float aN = acc[2][mf][nf][r];
                    float rg = __builtin_amdgcn_rcpf(1.f + __expf(-(xr + aR)));
                    float ig = __builtin_amdgcn_rcpf(1.f + __expf(-(xi + aI)));
                    float tz = xn + rg * aN;
                    tz = fminf(fmaxf(tz, -15.f), 15.f);
                    float e2x = __expf(2.f * tz);
                    float nn = (e2x - 1.f) * __builtin_amdgcn_rcpf(e2x + 1.f);
                    size_t o = (size_t)grow * 256 + col;
                    float nh = (1.f - ig) * nn + ig * hidden[o];
                    Cf[o] = nh;
                    Cb[o] = (bf16)nh;
                }
        }
    } else {
#pragma unroll
        for (int mf = 0; mf < 2; ++mf)
#pragma unroll
            for (int nf = 0; nf < 2; ++nf)
#pragma unroll
                for (int r = 0; r < 4; ++r) {
                    int grow = bm + wr_ * 32 + mf * 16 + l4 * 4 + r;
                    int col = bn + wc_ * 32 + nf * 16 + l15;
                    float v = acc[0][mf][nf][r];
                    if constexpr (MODE == 1) v = v * scale + bias[col];
                    if constexpr (MODE == 2) v = fmaxf(v + bias[col], 0.f);
                    Cb[(size_t)grow * N + col] = (bf16)v;
                }
    }
}

// ---------------------------------------------------------------------------
// Edge aggregation v4: packed channel pairs.
// Grid 1024: blk = b*16 + dgrp. 256 threads = 256 channel PAIRS, 4 dst each.
// f32x2 math -> v_pk_add/v_pk_fma; 8 independent acc chains for ILP.
// S[b,d,ch] = sum_src elu(w*(P+Q)+b1) - elu(b1)  (self term cancels exactly)
// ---------------------------------------------------------------------------
__global__ __launch_bounds__(256) void edge_agg_kernel(
    const bf16* __restrict__ PQ, const float* __restrict__ edges,
    const float* __restrict__ b1, bf16* __restrict__ S)
{
    const int blk = blockIdx.x;
    const int dgrp = blk & 15;
    const int b = blk >> 4;
    const int tid = threadIdx.x;
    const int d0 = dgrp * 4;

    __shared__ __align__(16) float wls[64][4];
    {
        int src = tid >> 2, dd = tid & 3;
        int d = d0 + dd;
        float w = 0.f;
        if (src != d) {
            int e = src * 63 + (d < src ? d : d - 1);
            float2 ev = ((const float2*)edges)[e];
            w = fmaxf(ev.x, ev.y);
        }
        wls[src][dd] = w;
    }
    __syncthreads();

    const bf16* Pb = PQ + (size_t)(b * 64) * 1024;
    f32x2 p2[4];
#pragma unroll
    for (int dd = 0; dd < 4; ++dd)
        p2[dd] = unpk(*(const unsigned int*)(Pb + (size_t)(d0 + dd) * 1024 + 2 * tid));
    float2 bbl = *(const float2*)(b1 + 2 * tid);
    f32x2 bb; bb.x = bbl.x; bb.y = bbl.y;
    const unsigned int* Qp = (const unsigned int*)(Pb + 512) + tid;

    f32x2 acc[4];
#pragma unroll
    for (int dd = 0; dd < 4; ++dd) acc[dd] = (f32x2){0.f, 0.f};

#pragma unroll 4
    for (int src = 0; src < 64; ++src) {
        f32x2 q = unpk(Qp[(size_t)src * 512]);
        float4 wv = *(const float4*)&wls[src][0];
        float w[4] = {wv.x, wv.y, wv.z, wv.w};
#pragma unroll
        for (int dd = 0; dd < 4; ++dd) {
            f32x2 w2; w2.x = w[dd]; w2.y = w[dd];
            f32x2 v = (p2[dd] + q) * w2 + bb;
            float e0 = __expf(v.x) - 1.f;
            float e1 = __expf(v.y) - 1.f;
            f32x2 r;
            r.x = (v.x > 0.f) ? v.x : e0;
            r.y = (v.y > 0.f) ? v.y : e1;
            acc[dd] += r;
        }
    }
    f32x2 selfc;
    selfc.x = (bb.x > 0.f) ? bb.x : (__expf(bb.x) - 1.f);
    selfc.y = (bb.y > 0.f) ? bb.y : (__expf(bb.y) - 1.f);
#pragma unroll
    for (int dd = 0; dd < 4; ++dd) {
        bf16x2 st;
        st[0] = (bf16)(acc[dd].x - selfc.x);
        st[1] = (bf16)(acc[dd].y - selfc.y);
        *(bf16x2*)(S + (size_t)(b * 64 + d0 + dd) * 512 + 2 * tid) = st;
    }
}

// ---------------------------------------------------------------------------
// pred[row,f] = inputs[row,f] + H2[row,:] @ f3_w[:,f] + f3_b[f]
// ---------------------------------------------------------------------------
__global__ __launch_bounds__(256) void pred_kernel(
    const float* __restrict__ inputs, const bf16* __restrict__ H2,
    const float* __restrict__ f3_w, const float* __restrict__ f3_b,
    float* __restrict__ pred)
{
    __shared__ float f3s[2048];
    for (int i = threadIdx.x; i < 2048; i += 256) f3s[i] = f3_w[i];
    __syncthreads();

    const int idx = blockIdx.x * 256 + threadIdx.x;
    const int row = idx >> 3, f = idx & 7;
    const bf16* hr = H2 + (size_t)row * 256;
    float a = f3_b[f];
    for (int k0 = 0; k0 < 256; k0 += 8) {
        bf16x8 h8 = *(const bf16x8*)(hr + k0);
#pragma unroll
        for (int j = 0; j < 8; ++j)
            a += (float)h8[j] * f3s[(k0 + j) * 8 + f];
    }
    pred[idx] = inputs[idx] + a;
}

// ---------------------------------------------------------------------------
extern "C" void kernel_launch(void* const* d_in, const int* in_sizes, int n_in,
                              void* d_out, int out_size, void* d_ws, size_t ws_size,
                              hipStream_t stream) {
    const float* inputs = (const float*)d_in[0];
    const float* hidden = (const float*)d_in[1];
    const float* edges  = (const float*)d_in[2];
    const float* ed_w1 = (const float*)d_in[4];
    const float* ed_b1 = (const float*)d_in[5];
    const float* ed_w2 = (const float*)d_in[6];
    const float* ed_b2 = (const float*)d_in[7];
    const float* wr = (const float*)d_in[8];
    const float* wi = (const float*)d_in[9];
    const float* wh = (const float*)d_in[10];
    const float* ir_w = (const float*)d_in[11];
    const float* ir_b = (const float*)d_in[12];
    const float* ii_w = (const float*)d_in[13];
    const float* ii_b = (const float*)d_in[14];
    const float* in_w = (const float*)d_in[15];
    const float* in_b = (const float*)d_in[16];
    const float* f1_w = (const float*)d_in[17];
    const float* f1_b = (const float*)d_in[18];
    const float* f2_w = (const float*)d_in[19];
    const float* f2_b = (const float*)d_in[20];
    const float* f3_w = (const float*)d_in[21];
    const float* f3_b = (const float*)d_in[22];

    float* out = (float*)d_out;
    float* pred = out;
    float* NH = out + (size_t)BB * NN * FF;

    // bf16 workspace layout (element offsets)
    bf16* bws = (bf16*)d_ws;
    bf16* PQ   = bws;              // 4096*1024
    bf16* Sb   = bws + 4194304;    // 4096*512
    bf16* AGGb = bws + 6291456;    // 4096*256
    bf16* NHb  = bws + 7340032;    // 4096*256
    bf16* H1b  = bws + 8388608;    // 4096*256
    bf16* H2b  = bws + 9437184;    // 4096*256
    bf16* hbf  = bws + 10485760;   // 4096*256
    bf16* W1t  = bws + 11534336;   // 1024*256
    bf16* W2t  = bws + 11796480;   // 256*512
    bf16* Wg   = bws + 11927552;   // 3*256*256
    bf16* f1t  = bws + 12124160;   // 256*256
    bf16* f2t  = bws + 12189696;   // 256*256

    dim3 blk(256);

    pack_kernel<<<dim3(1200), blk, 0, stream>>>(
        hidden, ed_w1, ed_w2, wr, wi, wh, f1_w, f2_w,
        hbf, W1t, W2t, Wg, f1t, f2t);

    // G1: PQ = hidden @ [W1top | W1bot]   (4096,1024,256)
    mfma_gemm<0><<<dim3(16, 64), blk, 0, stream>>>(
        hbf, W1t, nullptr, nullptr, PQ, 1024, 256, 1.f,
        nullptr, nullptr, nullptr, nullptr, nullptr, nullptr, nullptr, nullptr);

    // S: per-(b,d) elu-sum over sources (packed pairs)
    edge_agg_kernel<<<dim3(1024), blk, 0, stream>>>(PQ, edges, ed_b1, Sb);

    // G2: agg = S @ ed_w2 / 63 + ed_b2    (4096,256,512)
    mfma_gemm<1><<<dim3(4, 64), blk, 0, stream>>>(
        Sb, W2t, ed_b2, nullptr, AGGb, 256, 512, 1.f / 63.f,
        nullptr, nullptr, nullptr, nullptr, nullptr, nullptr, nullptr, nullptr);

    // G3: gates + fused GRU -> NH (fp32 out) + NHb (bf16)
    mfma_gemm<3><<<dim3(4, 64), blk, 0, stream>>>(
        AGGb, Wg, nullptr, NH, NHb, 256, 256, 1.f,
        inputs, hidden, ir_w, ir_b, ii_w, ii_b, in_w, in_b);

    // f1, f2 (relu)
    mfma_gemm<2><<<dim3(4, 64), blk, 0, stream>>>(
        NHb, f1t, f1_b, nullptr, H1b, 256, 256, 1.f,
        nullptr, nullptr, nullptr, nullptr, nullptr, nullptr, nullptr, nullptr);
    mfma_gemm<2><<<dim3(4, 64), blk, 0, stream>>>(
        H1b, f2t, f2_b, nullptr, H2b, 256, 256, 1.f,
        nullptr, nullptr, nullptr, nullptr, nullptr, nullptr, nullptr, nullptr);

    pred_kernel<<<dim3(128), blk, 0, stream>>>(inputs, H2b, f3_w, f3_b, pred);
}